// Round 8
// baseline (169.568 us; speedup 1.0000x reference)
//
#include <hip/hip_runtime.h>

// CausalSelfAttention: B=4 T=1024 C=768 NH=12 HD=64, start_pos=0.
// Round 8: k_attn 128 q-rows/block (4 waves x 32 rows) — halves K/V staging
//   traffic (104->55 MB L2) and amortizes K/V LDS frag reads over 2 row-halves;
//   per-row-half chunk skip (wave-uniform); longest-tile-first. k_prep merges
//   cvt + both weight transposes into one launch. GEMMs unchanged.
// MFMA 16x16x32 bf16 layouts (HW-verified per guide):
//   A-op:  A[m=lane&15][k=(lane>>4)*8+j]   (8 bf16 / lane, contiguous in k)
//   B-op:  B[k=(lane>>4)*8+j][n=lane&15]   (contiguous in k)
//   C/D :  C[row=(lane>>4)*4+reg][col=lane&15]

#define BB 4
#define TT 1024
#define CC 768
#define NHH 12
#define HDD 64
#define BHH (BB*NHH)

typedef unsigned short u16;
typedef __attribute__((ext_vector_type(8))) short bf16x8;
typedef __attribute__((ext_vector_type(4))) float f32x4;

__device__ __forceinline__ u16 f2b(float f) {
  unsigned u = __float_as_uint(f);
  u += 0x7fffu + ((u >> 16) & 1u);   // RTNE
  return (u16)(u >> 16);
}
__device__ __forceinline__ u16 f2b_t(float f) {  // truncating (P values in [0,1])
  return (u16)(__float_as_uint(f) >> 16);
}

// async global->LDS, 16B per lane; LDS dest must be wave-uniform base + lane*16
__device__ __forceinline__ void gload_lds16(const u16* g, u16* l) {
  __builtin_amdgcn_global_load_lds(
      (const __attribute__((address_space(1))) unsigned int*)g,
      (__attribute__((address_space(3))) unsigned int*)l, 16, 0, 0);
}

// ---------- fused prep: x fp32->bf16 cvt  +  Wqkv / Wproj transposes ----------
__device__ __forceinline__ void tr_body(const float* __restrict__ in, u16* __restrict__ out,
                                        int R, int Cc, int bx, int by, float (*tile)[33]) {
  int c0 = bx * 32, r0 = by * 32;
  int tx = threadIdx.x & 31, ty = threadIdx.x >> 5;  // 32 x 8
#pragma unroll
  for (int i = 0; i < 32; i += 8)
    tile[ty + i][tx] = in[(r0 + ty + i) * Cc + c0 + tx];
  __syncthreads();
#pragma unroll
  for (int i = 0; i < 32; i += 8)
    out[(c0 + ty + i) * R + r0 + tx] = f2b(tile[tx][ty + i]);
}

__global__ __launch_bounds__(256) void k_prep(const float* __restrict__ x, u16* __restrict__ xb,
                                              const float* __restrict__ Wqkv, u16* __restrict__ Wqkv_t,
                                              const float* __restrict__ Wproj, u16* __restrict__ Wproj_t) {
  __shared__ float tile[32][33];
  int bid = blockIdx.x;
  if (bid < 3072) {                       // cvt: 786432 float4 groups
    int i = bid * 256 + threadIdx.x;
    float4 v = ((const float4*)x)[i];
    ushort4 o;
    o.x = f2b(v.x); o.y = f2b(v.y); o.z = f2b(v.z); o.w = f2b(v.w);
    ((ushort4*)xb)[i] = o;
  } else if (bid < 3072 + 1728) {         // Wqkv [768 x 2304] -> [2304 x 768]
    int tb = bid - 3072;
    tr_body(Wqkv, Wqkv_t, CC, 3 * CC, tb % 72, tb / 72, tile);
  } else {                                // Wproj [768 x 768] -> [768 x 768]
    int tb = bid - 4800;
    tr_body(Wproj, Wproj_t, CC, CC, tb % 24, tb / 24, tile);
  }
}

// ============ shared GEMM core: 128x128 tile, BK=32, 4 waves, 4x4 frags/wave ============
#define GEMM_CORE(A_, Bt_, m0_, n0_, SMEM)                                        \
  u16* As = (SMEM); u16* Bs = (SMEM) + 4096;                                      \
  int tid = threadIdx.x;                                                          \
  int wave = tid >> 6, lane = tid & 63, quad = lane >> 4, id16 = lane & 15;       \
  int wm = (wave & 1) * 64, wn = (wave >> 1) * 64;                                \
  const u16* ga = A_ + (m0_ + (tid >> 2)) * CC + (tid & 3) * 8;                   \
  const u16* gb = Bt_ + (n0_ + (tid >> 2)) * CC + (tid & 3) * 8;                  \
  f32x4 acc[4][4];                                                                \
  _Pragma("unroll") for (int i = 0; i < 4; i++)                                   \
      _Pragma("unroll") for (int j = 0; j < 4; j++) acc[i][j] = (f32x4){0,0,0,0}; \
  for (int k0 = 0; k0 < CC; k0 += 32) {                                           \
    gload_lds16(ga + k0, As + tid * 8);                                           \
    gload_lds16(ga + 64 * CC + k0, As + 64 * 32 + tid * 8);                       \
    gload_lds16(gb + k0, Bs + tid * 8);                                           \
    gload_lds16(gb + 64 * CC + k0, Bs + 64 * 32 + tid * 8);                       \
    __syncthreads();                                                              \
    bf16x8 af[4], bfr[4];                                                         \
    _Pragma("unroll") for (int i = 0; i < 4; i++)                                 \
        af[i] = *(const bf16x8*)(As + (wm + i * 16 + id16) * 32 + quad * 8);      \
    _Pragma("unroll") for (int j = 0; j < 4; j++)                                 \
        bfr[j] = *(const bf16x8*)(Bs + (wn + j * 16 + id16) * 32 + quad * 8);     \
    _Pragma("unroll") for (int i = 0; i < 4; i++)                                 \
        _Pragma("unroll") for (int j = 0; j < 4; j++)                             \
            acc[i][j] = __builtin_amdgcn_mfma_f32_16x16x32_bf16(af[i], bfr[j],    \
                                                                acc[i][j], 0, 0, 0); \
    __syncthreads();                                                              \
  }

// ---------- QKV GEMM: xb[4096x768] @ Wqkv_t^T + bias, scatter Qb/Kb, transpose Vt ----------
__global__ __launch_bounds__(256) void k_qkv(const u16* __restrict__ A, const u16* __restrict__ Bt,
                                             const float* __restrict__ bias,
                                             u16* __restrict__ Qb, u16* __restrict__ Kb,
                                             u16* __restrict__ Vt) {
  __shared__ u16 smem[128 * 136];   // GEMM uses [0,8192); V-transpose uses all
  int m0 = (blockIdx.x / 18) * 128, n0 = (blockIdx.x % 18) * 128;
  GEMM_CORE(A, Bt, m0, n0, smem)
  float bv[4];
#pragma unroll
  for (int j = 0; j < 4; j++) bv[j] = bias[n0 + wn + j * 16 + id16];

  if (n0 < 2 * CC) {
    u16* dstb = (n0 < CC) ? Qb : Kb;
    int nrel0 = (n0 < CC) ? n0 : n0 - CC;
#pragma unroll
    for (int i = 0; i < 4; i++) {
#pragma unroll
      for (int j = 0; j < 4; j++) {
#pragma unroll
        for (int r = 0; r < 4; r++) {
          int m = m0 + wm + i * 16 + quad * 4 + r;
          int n = nrel0 + wn + j * 16 + id16;
          int bi = m >> 10, ti = m & 1023;
          dstb[((bi * NHH + (n >> 6)) * TT + ti) * HDD + (n & 63)] =
              f2b(acc[i][j][r] + bv[j]);
        }
      }
    }
  } else {
    // V: LDS transpose (stride 136 u16), then coalesced Vt[d][t] row stores
#pragma unroll
    for (int i = 0; i < 4; i++)
#pragma unroll
      for (int j = 0; j < 4; j++)
#pragma unroll
        for (int r = 0; r < 4; r++)
          smem[(wn + j * 16 + id16) * 136 + wm + i * 16 + quad * 4 + r] =
              f2b(acc[i][j][r] + bv[j]);
    __syncthreads();
    int d2 = tid >> 1, seg = tid & 1;
    int h = (n0 - 2 * CC + d2) >> 6;
    int d = d2 & 63;
    int bi = m0 >> 10, t0 = m0 & 1023;
    u16* dst = Vt + (((bi * NHH + h) * HDD + d) * TT) + t0 + seg * 64;
    const u16* src = smem + d2 * 136 + seg * 64;
#pragma unroll
    for (int w2 = 0; w2 < 8; w2++)
      ((bf16x8*)dst)[w2] = ((const bf16x8*)src)[w2];
  }
}

// ---------- Proj GEMM: Ob[4096x768] @ Wproj_t^T + bias -> out fp32 ----------
__global__ __launch_bounds__(256) void k_proj(const u16* __restrict__ A, const u16* __restrict__ Bt,
                                              const float* __restrict__ bias, float* __restrict__ out) {
  __shared__ u16 smem[8192];
  int m0 = (blockIdx.x / 6) * 128, n0 = (blockIdx.x % 6) * 128;
  GEMM_CORE(A, Bt, m0, n0, smem)
  float bv[4];
#pragma unroll
  for (int j = 0; j < 4; j++) bv[j] = bias[n0 + wn + j * 16 + id16];
#pragma unroll
  for (int i = 0; i < 4; i++) {
#pragma unroll
    for (int j = 0; j < 4; j++) {
#pragma unroll
      for (int r = 0; r < 4; r++) {
        int m = m0 + wm + i * 16 + quad * 4 + r;
        int n = n0 + wn + j * 16 + id16;
        out[m * CC + n] = acc[i][j][r] + bv[j];
      }
    }
  }
}

// ---------- Flash attention: 128 q-rows/block, LDS-shared K/V ----------
// grid = 384 blocks x 256 thr. bh = blockIdx%48 (XCD-local), t = 7-blockIdx/48
// (longest first). Wave w owns 32 q-rows (two 16-row halves). 64-key chunks
// staged via global_load_lds, double-buffered, one barrier/chunk. K/V frags
// read once per chunk, reused across both row-halves. Row-half skips chunks
// entirely below it (wave-uniform); mask only on its diagonal chunk.
#define PSTR 72
__global__ __launch_bounds__(256) void k_attn(const u16* __restrict__ Qb, const u16* __restrict__ Kb,
                                              const u16* __restrict__ Vt, u16* __restrict__ Ob) {
  __shared__ __align__(16) u16 Ks[2][64 * 64];    // [buf][key][d]
  __shared__ __align__(16) u16 Vs[2][64 * 64];    // [buf][d][key]
  __shared__ __align__(16) u16 Pl[4][32 * PSTR];  // per-wave P (32 x 64, stride 72)
  int tid = threadIdx.x;
  int wave = tid >> 6, lane = tid & 63, quad = lane >> 4, id16 = lane & 15;
  int bh = blockIdx.x % BHH, t = 7 - (blockIdx.x / BHH);
  int b = bh / NHH, h = bh % NHH;
  int qw = t * 128 + wave * 32;     // this wave's first q row
  int nch = 2 * t + 2;              // 64-key chunks this block runs
  const float cexp = 0.125f * 1.44269504088896f;  // scale * log2(e)
  short onev = (id16 == 0) ? (short)0x3F80 : (short)0;  // bf16 1.0 on col 0
  bf16x8 bones = {onev, onev, onev, onev, onev, onev, onev, onev};

  const u16* Kg = Kb + (bh * TT) * HDD;        // [T][64]
  const u16* Vg = Vt + (bh * HDD) * TT;        // [64][T]
  int vrow = tid >> 3, vpart = tid & 7;        // V staging coords

  bf16x8 aq[2][2];
#pragma unroll
  for (int rh = 0; rh < 2; rh++) {
    const u16* Qrow = Qb + (bh * TT + qw + 16 * rh + id16) * HDD;
    aq[rh][0] = *(const bf16x8*)(Qrow + quad * 8);
    aq[rh][1] = *(const bf16x8*)(Qrow + 32 + quad * 8);
  }
  f32x4 o[2][4], ol[2];
#pragma unroll
  for (int rh = 0; rh < 2; rh++) {
    ol[rh] = (f32x4){0,0,0,0};
#pragma unroll
    for (int dt = 0; dt < 4; dt++) o[rh][dt] = (f32x4){0,0,0,0};
  }
  int cr[2] = {(qw + 15) >> 6, (qw + 31) >> 6};  // diagonal chunk per row-half

  // stage chunk 0 into buf 0
  gload_lds16(Kg + tid * 8, Ks[0] + tid * 8);
  gload_lds16(Kg + 2048 + tid * 8, Ks[0] + 2048 + tid * 8);
  gload_lds16(Vg + vrow * TT + vpart * 8, Vs[0] + tid * 8);
  gload_lds16(Vg + (32 + vrow) * TT + vpart * 8, Vs[0] + 2048 + tid * 8);

  for (int c = 0; c < nch; c++) {
    __syncthreads();
    if (c + 1 < nch) {
      int kb = (c + 1) * 64;
      u16* kd = Ks[(c + 1) & 1];
      u16* vd = Vs[(c + 1) & 1];
      const u16* kg = Kg + kb * HDD;
      gload_lds16(kg + tid * 8, kd + tid * 8);
      gload_lds16(kg + 2048 + tid * 8, kd + 2048 + tid * 8);
      gload_lds16(Vg + vrow * TT + kb + vpart * 8, vd + tid * 8);
      gload_lds16(Vg + (32 + vrow) * TT + kb + vpart * 8, vd + 2048 + tid * 8);
    }
    const u16* kbuf = Ks[c & 1];
    const u16* vbuf = Vs[c & 1];

    // K frags, read once, reused for both row-halves
    bf16x8 kf0[4], kf1[4];
#pragma unroll
    for (int kt = 0; kt < 4; kt++) {
      kf0[kt] = *(const bf16x8*)(kbuf + (kt * 16 + id16) * 64 + quad * 8);
      kf1[kt] = *(const bf16x8*)(kbuf + (kt * 16 + id16) * 64 + 32 + quad * 8);
    }

    u16* Pb = Pl[wave];
#pragma unroll
    for (int rh = 0; rh < 2; rh++) {
      if (c > cr[rh]) continue;  // chunk entirely above this row-half (wave-uniform)
      f32x4 s[4];
#pragma unroll
      for (int kt = 0; kt < 4; kt++) {
        f32x4 z = {0,0,0,0};
        z = __builtin_amdgcn_mfma_f32_16x16x32_bf16(aq[rh][0], kf0[kt], z, 0, 0, 0);
        s[kt] = __builtin_amdgcn_mfma_f32_16x16x32_bf16(aq[rh][1], kf1[kt], z, 0, 0, 0);
      }
      if (c < cr[rh]) {
#pragma unroll
        for (int kt = 0; kt < 4; kt++)
#pragma unroll
          for (int r = 0; r < 4; r++)
            Pb[(16 * rh + quad * 4 + r) * PSTR + kt * 16 + id16] =
                f2b_t(__builtin_amdgcn_exp2f(s[kt][r] * cexp));
      } else {  // diagonal chunk for this row-half: causal mask
        int kb = c * 64;
#pragma unroll
        for (int kt = 0; kt < 4; kt++) {
          int col = kb + kt * 16 + id16;
#pragma unroll
          for (int r = 0; r < 4; r++) {
            float p = __builtin_amdgcn_exp2f(s[kt][r] * cexp);
            p = (col <= qw + 16 * rh + quad * 4 + r) ? p : 0.f;
            Pb[(16 * rh + quad * 4 + r) * PSTR + kt * 16 + id16] = f2b_t(p);
          }
        }
      }
    }
    asm volatile("s_waitcnt lgkmcnt(0)" ::: "memory");

    bf16x8 pf[2][2];
#pragma unroll
    for (int rh = 0; rh < 2; rh++) {
      if (c > cr[rh]) continue;
      pf[rh][0] = *(const bf16x8*)(Pb + (16 * rh + id16) * PSTR + quad * 8);
      pf[rh][1] = *(const bf16x8*)(Pb + (16 * rh + id16) * PSTR + 32 + quad * 8);
    }
    // O += P @ V  (4 d-tiles), V frags shared across row-halves; l via ones
#pragma unroll
    for (int dt = 0; dt < 4; dt++) {
      bf16x8 vf0 = *(const bf16x8*)(vbuf + (dt * 16 + id16) * 64 + quad * 8);
      bf16x8 vf1 = *(const bf16x8*)(vbuf + (dt * 16 + id16) * 64 + 32 + quad * 8);
#pragma unroll
      for (int rh = 0; rh < 2; rh++) {
        if (c > cr[rh]) continue;
        o[rh][dt] = __builtin_amdgcn_mfma_f32_16x16x32_bf16(pf[rh][0], vf0, o[rh][dt], 0, 0, 0);
        o[rh][dt] = __builtin_amdgcn_mfma_f32_16x16x32_bf16(pf[rh][1], vf1, o[rh][dt], 0, 0, 0);
      }
    }
#pragma unroll
    for (int rh = 0; rh < 2; rh++) {
      if (c > cr[rh]) continue;
      ol[rh] = __builtin_amdgcn_mfma_f32_16x16x32_bf16(pf[rh][0], bones, ol[rh], 0, 0, 0);
      ol[rh] = __builtin_amdgcn_mfma_f32_16x16x32_bf16(pf[rh][1], bones, ol[rh], 0, 0, 0);
    }
  }

#pragma unroll
  for (int rh = 0; rh < 2; rh++) {
    int outbase = (b * TT + qw + 16 * rh + quad * 4) * CC + h * HDD;
#pragma unroll
    for (int r = 0; r < 4; r++) {
      float l = __shfl(ol[rh][r], 0, 16);
      float inv = 1.0f / l;
      Ob[outbase + r * CC + id16]      = f2b(o[rh][0][r] * inv);
      Ob[outbase + r * CC + 16 + id16] = f2b(o[rh][1][r] * inv);
      Ob[outbase + r * CC + 32 + id16] = f2b(o[rh][2][r] * inv);
      Ob[outbase + r * CC + 48 + id16] = f2b(o[rh][3][r] * inv);
    }
  }
}

extern "C" void kernel_launch(void* const* d_in, const int* in_sizes, int n_in,
                              void* d_out, int out_size, void* d_ws, size_t ws_size,
                              hipStream_t stream) {
  const float* x     = (const float*)d_in[0];
  const float* Wqkv  = (const float*)d_in[1];
  const float* bqkv  = (const float*)d_in[2];
  const float* Wproj = (const float*)d_in[3];
  const float* bproj = (const float*)d_in[4];
  // d_in[5] = start_pos (always 0; KV-cache write+slice is identity)
  float* out = (float*)d_out;

  u16* ws = (u16*)d_ws;
  u16* xb      = ws;                              // [4096 x 768]
  u16* Wqkv_t  = xb + BB * TT * CC;               // [2304 x 768]
  u16* Wproj_t = Wqkv_t + 3 * CC * CC;            // [768 x 768]
  u16* Qb      = Wproj_t + CC * CC;               // [BH][T][64]
  u16* Kb      = Qb + BHH * TT * HDD;             // [BH][T][64]
  u16* Vt      = Kb + BHH * TT * HDD;             // [BH][64][T]
  u16* Ob      = Vt + BHH * TT * HDD;             // [4096 x 768]

  k_prep<<<3072 + 1728 + 576, 256, 0, stream>>>(x, xb, Wqkv, Wqkv_t, Wproj, Wproj_t);
  k_qkv<<<32 * 18, 256, 0, stream>>>(xb, Wqkv_t, bqkv, Qb, Kb, Vt);
  k_attn<<<8 * BHH, 256, 0, stream>>>(Qb, Kb, Vt, Ob);
  k_proj<<<32 * 6, 256, 0, stream>>>(Ob, Wproj_t, bproj, out);
}

// Round 9
// 161.938 us; speedup vs baseline: 1.0471x; 1.0471x over previous
//
#include <hip/hip_runtime.h>

// CausalSelfAttention: B=4 T=1024 C=768 NH=12 HD=64, start_pos=0.
// Round 9: k_attn = R7 grid (768 blocks, 64 q-rows, longest-first, XCD swizzle)
//   but 2 waves x 32 q-rows (128 thr): K/V LDS frag reads amortized over two
//   16-row halves -> LDS read traffic per block-chunk halved vs R7, with R7's
//   load balance (R8's 384-block version regressed on imbalance). All row-
//   halves share the block diagonal -> mask only on last chunk, no skips.
// GEMMs + k_prep unchanged.
// MFMA 16x16x32 bf16 layouts (HW-verified per guide):
//   A-op:  A[m=lane&15][k=(lane>>4)*8+j]   (8 bf16 / lane, contiguous in k)
//   B-op:  B[k=(lane>>4)*8+j][n=lane&15]   (contiguous in k)
//   C/D :  C[row=(lane>>4)*4+reg][col=lane&15]

#define BB 4
#define TT 1024
#define CC 768
#define NHH 12
#define HDD 64
#define BHH (BB*NHH)

typedef unsigned short u16;
typedef __attribute__((ext_vector_type(8))) short bf16x8;
typedef __attribute__((ext_vector_type(4))) float f32x4;

__device__ __forceinline__ u16 f2b(float f) {
  unsigned u = __float_as_uint(f);
  u += 0x7fffu + ((u >> 16) & 1u);   // RTNE
  return (u16)(u >> 16);
}
__device__ __forceinline__ u16 f2b_t(float f) {  // truncating (P values in [0,1])
  return (u16)(__float_as_uint(f) >> 16);
}

// async global->LDS, 16B per lane; LDS dest must be wave-uniform base + lane*16
__device__ __forceinline__ void gload_lds16(const u16* g, u16* l) {
  __builtin_amdgcn_global_load_lds(
      (const __attribute__((address_space(1))) unsigned int*)g,
      (__attribute__((address_space(3))) unsigned int*)l, 16, 0, 0);
}

// ---------- fused prep: x fp32->bf16 cvt  +  Wqkv / Wproj transposes ----------
__device__ __forceinline__ void tr_body(const float* __restrict__ in, u16* __restrict__ out,
                                        int R, int Cc, int bx, int by, float (*tile)[33]) {
  int c0 = bx * 32, r0 = by * 32;
  int tx = threadIdx.x & 31, ty = threadIdx.x >> 5;  // 32 x 8
#pragma unroll
  for (int i = 0; i < 32; i += 8)
    tile[ty + i][tx] = in[(r0 + ty + i) * Cc + c0 + tx];
  __syncthreads();
#pragma unroll
  for (int i = 0; i < 32; i += 8)
    out[(c0 + ty + i) * R + r0 + tx] = f2b(tile[tx][ty + i]);
}

__global__ __launch_bounds__(256) void k_prep(const float* __restrict__ x, u16* __restrict__ xb,
                                              const float* __restrict__ Wqkv, u16* __restrict__ Wqkv_t,
                                              const float* __restrict__ Wproj, u16* __restrict__ Wproj_t) {
  __shared__ float tile[32][33];
  int bid = blockIdx.x;
  if (bid < 3072) {                       // cvt: 786432 float4 groups
    int i = bid * 256 + threadIdx.x;
    float4 v = ((const float4*)x)[i];
    ushort4 o;
    o.x = f2b(v.x); o.y = f2b(v.y); o.z = f2b(v.z); o.w = f2b(v.w);
    ((ushort4*)xb)[i] = o;
  } else if (bid < 3072 + 1728) {         // Wqkv [768 x 2304] -> [2304 x 768]
    int tb = bid - 3072;
    tr_body(Wqkv, Wqkv_t, CC, 3 * CC, tb % 72, tb / 72, tile);
  } else {                                // Wproj [768 x 768] -> [768 x 768]
    int tb = bid - 4800;
    tr_body(Wproj, Wproj_t, CC, CC, tb % 24, tb / 24, tile);
  }
}

// ============ shared GEMM core: 128x128 tile, BK=32, 4 waves, 4x4 frags/wave ============
#define GEMM_CORE(A_, Bt_, m0_, n0_, SMEM)                                        \
  u16* As = (SMEM); u16* Bs = (SMEM) + 4096;                                      \
  int tid = threadIdx.x;                                                          \
  int wave = tid >> 6, lane = tid & 63, quad = lane >> 4, id16 = lane & 15;       \
  int wm = (wave & 1) * 64, wn = (wave >> 1) * 64;                                \
  const u16* ga = A_ + (m0_ + (tid >> 2)) * CC + (tid & 3) * 8;                   \
  const u16* gb = Bt_ + (n0_ + (tid >> 2)) * CC + (tid & 3) * 8;                  \
  f32x4 acc[4][4];                                                                \
  _Pragma("unroll") for (int i = 0; i < 4; i++)                                   \
      _Pragma("unroll") for (int j = 0; j < 4; j++) acc[i][j] = (f32x4){0,0,0,0}; \
  for (int k0 = 0; k0 < CC; k0 += 32) {                                           \
    gload_lds16(ga + k0, As + tid * 8);                                           \
    gload_lds16(ga + 64 * CC + k0, As + 64 * 32 + tid * 8);                       \
    gload_lds16(gb + k0, Bs + tid * 8);                                           \
    gload_lds16(gb + 64 * CC + k0, Bs + 64 * 32 + tid * 8);                       \
    __syncthreads();                                                              \
    bf16x8 af[4], bfr[4];                                                         \
    _Pragma("unroll") for (int i = 0; i < 4; i++)                                 \
        af[i] = *(const bf16x8*)(As + (wm + i * 16 + id16) * 32 + quad * 8);      \
    _Pragma("unroll") for (int j = 0; j < 4; j++)                                 \
        bfr[j] = *(const bf16x8*)(Bs + (wn + j * 16 + id16) * 32 + quad * 8);     \
    _Pragma("unroll") for (int i = 0; i < 4; i++)                                 \
        _Pragma("unroll") for (int j = 0; j < 4; j++)                             \
            acc[i][j] = __builtin_amdgcn_mfma_f32_16x16x32_bf16(af[i], bfr[j],    \
                                                                acc[i][j], 0, 0, 0); \
    __syncthreads();                                                              \
  }

// ---------- QKV GEMM: xb[4096x768] @ Wqkv_t^T + bias, scatter Qb/Kb, transpose Vt ----------
__global__ __launch_bounds__(256) void k_qkv(const u16* __restrict__ A, const u16* __restrict__ Bt,
                                             const float* __restrict__ bias,
                                             u16* __restrict__ Qb, u16* __restrict__ Kb,
                                             u16* __restrict__ Vt) {
  __shared__ u16 smem[128 * 136];   // GEMM uses [0,8192); V-transpose uses all
  int m0 = (blockIdx.x / 18) * 128, n0 = (blockIdx.x % 18) * 128;
  GEMM_CORE(A, Bt, m0, n0, smem)
  float bv[4];
#pragma unroll
  for (int j = 0; j < 4; j++) bv[j] = bias[n0 + wn + j * 16 + id16];

  if (n0 < 2 * CC) {
    u16* dstb = (n0 < CC) ? Qb : Kb;
    int nrel0 = (n0 < CC) ? n0 : n0 - CC;
#pragma unroll
    for (int i = 0; i < 4; i++) {
#pragma unroll
      for (int j = 0; j < 4; j++) {
#pragma unroll
        for (int r = 0; r < 4; r++) {
          int m = m0 + wm + i * 16 + quad * 4 + r;
          int n = nrel0 + wn + j * 16 + id16;
          int bi = m >> 10, ti = m & 1023;
          dstb[((bi * NHH + (n >> 6)) * TT + ti) * HDD + (n & 63)] =
              f2b(acc[i][j][r] + bv[j]);
        }
      }
    }
  } else {
    // V: LDS transpose (stride 136 u16), then coalesced Vt[d][t] row stores
#pragma unroll
    for (int i = 0; i < 4; i++)
#pragma unroll
      for (int j = 0; j < 4; j++)
#pragma unroll
        for (int r = 0; r < 4; r++)
          smem[(wn + j * 16 + id16) * 136 + wm + i * 16 + quad * 4 + r] =
              f2b(acc[i][j][r] + bv[j]);
    __syncthreads();
    int d2 = tid >> 1, seg = tid & 1;
    int h = (n0 - 2 * CC + d2) >> 6;
    int d = d2 & 63;
    int bi = m0 >> 10, t0 = m0 & 1023;
    u16* dst = Vt + (((bi * NHH + h) * HDD + d) * TT) + t0 + seg * 64;
    const u16* src = smem + d2 * 136 + seg * 64;
#pragma unroll
    for (int w2 = 0; w2 < 8; w2++)
      ((bf16x8*)dst)[w2] = ((const bf16x8*)src)[w2];
  }
}

// ---------- Proj GEMM: Ob[4096x768] @ Wproj_t^T + bias -> out fp32 ----------
__global__ __launch_bounds__(256) void k_proj(const u16* __restrict__ A, const u16* __restrict__ Bt,
                                              const float* __restrict__ bias, float* __restrict__ out) {
  __shared__ u16 smem[8192];
  int m0 = (blockIdx.x / 6) * 128, n0 = (blockIdx.x % 6) * 128;
  GEMM_CORE(A, Bt, m0, n0, smem)
  float bv[4];
#pragma unroll
  for (int j = 0; j < 4; j++) bv[j] = bias[n0 + wn + j * 16 + id16];
#pragma unroll
  for (int i = 0; i < 4; i++) {
#pragma unroll
    for (int j = 0; j < 4; j++) {
#pragma unroll
      for (int r = 0; r < 4; r++) {
        int m = m0 + wm + i * 16 + quad * 4 + r;
        int n = n0 + wn + j * 16 + id16;
        out[m * CC + n] = acc[i][j][r] + bv[j];
      }
    }
  }
}

// ---------- Flash attention: 64 q-rows/block, 2 waves x 32 rows ----------
// grid = 768 blocks x 128 thr. bh = blockIdx%48 (XCD-local), t = 15-blockIdx/48
// (longest first). Wave owns 32 q-rows (two 16-row halves); K/V frags read once
// per chunk and reused for both halves. 64-key chunks staged via global_load_lds
// (8 x 16B/thread), double-buffered, one barrier/chunk. All row-halves share the
// block diagonal -> causal mask only on the last chunk.
#define PSTR 72
__global__ __launch_bounds__(128) void k_attn(const u16* __restrict__ Qb, const u16* __restrict__ Kb,
                                              const u16* __restrict__ Vt, u16* __restrict__ Ob) {
  __shared__ __align__(16) u16 Ks[2][64 * 64];    // [buf][key][d]
  __shared__ __align__(16) u16 Vs[2][64 * 64];    // [buf][d][key]
  __shared__ __align__(16) u16 Pl[2][32 * PSTR];  // per-wave P (32 x 64, stride 72)
  int tid = threadIdx.x;
  int wave = tid >> 6, lane = tid & 63, quad = lane >> 4, id16 = lane & 15;
  int bh = blockIdx.x % BHH, t = 15 - (blockIdx.x / BHH);
  int b = bh / NHH, h = bh % NHH;
  int qw = t * 64 + wave * 32;      // this wave's first q row
  int nch = t + 1;                  // 64-key chunks this block runs
  const float cexp = 0.125f * 1.44269504088896f;  // scale * log2(e)
  short onev = (id16 == 0) ? (short)0x3F80 : (short)0;  // bf16 1.0 on col 0
  bf16x8 bones = {onev, onev, onev, onev, onev, onev, onev, onev};

  const u16* Kg = Kb + (bh * TT) * HDD;        // [T][64]
  const u16* Vg = Vt + (bh * HDD) * TT;        // [64][T]
  int srow = tid >> 3, spart = tid & 7;        // staging coords (16 rows/gload)

  bf16x8 aq[2][2];
#pragma unroll
  for (int rh = 0; rh < 2; rh++) {
    const u16* Qrow = Qb + (bh * TT + qw + 16 * rh + id16) * HDD;
    aq[rh][0] = *(const bf16x8*)(Qrow + quad * 8);
    aq[rh][1] = *(const bf16x8*)(Qrow + 32 + quad * 8);
  }
  f32x4 o[2][4], ol[2];
#pragma unroll
  for (int rh = 0; rh < 2; rh++) {
    ol[rh] = (f32x4){0,0,0,0};
#pragma unroll
    for (int dt = 0; dt < 4; dt++) o[rh][dt] = (f32x4){0,0,0,0};
  }

  // stage chunk 0 into buf 0: K 4 gloads (16 key-rows each), V 4 gloads (16 d-rows each)
#pragma unroll
  for (int i = 0; i < 4; i++) {
    gload_lds16(Kg + (16 * i + srow) * HDD + spart * 8, Ks[0] + i * 1024 + tid * 8);
    gload_lds16(Vg + (16 * i + srow) * TT + spart * 8, Vs[0] + i * 1024 + tid * 8);
  }

  for (int c = 0; c < nch; c++) {
    __syncthreads();
    if (c + 1 < nch) {
      int kb = (c + 1) * 64;
      u16* kd = Ks[(c + 1) & 1];
      u16* vd = Vs[(c + 1) & 1];
#pragma unroll
      for (int i = 0; i < 4; i++) {
        gload_lds16(Kg + (kb + 16 * i + srow) * HDD + spart * 8, kd + i * 1024 + tid * 8);
        gload_lds16(Vg + (16 * i + srow) * TT + kb + spart * 8, vd + i * 1024 + tid * 8);
      }
    }
    const u16* kbuf = Ks[c & 1];
    const u16* vbuf = Vs[c & 1];

    // K frags: read once, reused for both row-halves
    bf16x8 kf0[4], kf1[4];
#pragma unroll
    for (int kt = 0; kt < 4; kt++) {
      kf0[kt] = *(const bf16x8*)(kbuf + (kt * 16 + id16) * 64 + quad * 8);
      kf1[kt] = *(const bf16x8*)(kbuf + (kt * 16 + id16) * 64 + 32 + quad * 8);
    }

    u16* Pb = Pl[wave];
    bool diag = (c == nch - 1);
#pragma unroll
    for (int rh = 0; rh < 2; rh++) {
      f32x4 s[4];
#pragma unroll
      for (int kt = 0; kt < 4; kt++) {
        f32x4 z = {0,0,0,0};
        z = __builtin_amdgcn_mfma_f32_16x16x32_bf16(aq[rh][0], kf0[kt], z, 0, 0, 0);
        s[kt] = __builtin_amdgcn_mfma_f32_16x16x32_bf16(aq[rh][1], kf1[kt], z, 0, 0, 0);
      }
      if (!diag) {
#pragma unroll
        for (int kt = 0; kt < 4; kt++)
#pragma unroll
          for (int r = 0; r < 4; r++)
            Pb[(16 * rh + quad * 4 + r) * PSTR + kt * 16 + id16] =
                f2b_t(__builtin_amdgcn_exp2f(s[kt][r] * cexp));
      } else {
        int kb = c * 64;
#pragma unroll
        for (int kt = 0; kt < 4; kt++) {
          int col = kb + kt * 16 + id16;
#pragma unroll
          for (int r = 0; r < 4; r++) {
            float p = __builtin_amdgcn_exp2f(s[kt][r] * cexp);
            p = (col <= qw + 16 * rh + quad * 4 + r) ? p : 0.f;
            Pb[(16 * rh + quad * 4 + r) * PSTR + kt * 16 + id16] = f2b_t(p);
          }
        }
      }
    }
    asm volatile("s_waitcnt lgkmcnt(0)" ::: "memory");

    bf16x8 pf[2][2];
#pragma unroll
    for (int rh = 0; rh < 2; rh++) {
      pf[rh][0] = *(const bf16x8*)(Pb + (16 * rh + id16) * PSTR + quad * 8);
      pf[rh][1] = *(const bf16x8*)(Pb + (16 * rh + id16) * PSTR + 32 + quad * 8);
    }
    // O += P @ V: V frags read once, reused for both row-halves; l via ones
#pragma unroll
    for (int dt = 0; dt < 4; dt++) {
      bf16x8 vf0 = *(const bf16x8*)(vbuf + (dt * 16 + id16) * 64 + quad * 8);
      bf16x8 vf1 = *(const bf16x8*)(vbuf + (dt * 16 + id16) * 64 + 32 + quad * 8);
#pragma unroll
      for (int rh = 0; rh < 2; rh++) {
        o[rh][dt] = __builtin_amdgcn_mfma_f32_16x16x32_bf16(pf[rh][0], vf0, o[rh][dt], 0, 0, 0);
        o[rh][dt] = __builtin_amdgcn_mfma_f32_16x16x32_bf16(pf[rh][1], vf1, o[rh][dt], 0, 0, 0);
      }
    }
#pragma unroll
    for (int rh = 0; rh < 2; rh++) {
      ol[rh] = __builtin_amdgcn_mfma_f32_16x16x32_bf16(pf[rh][0], bones, ol[rh], 0, 0, 0);
      ol[rh] = __builtin_amdgcn_mfma_f32_16x16x32_bf16(pf[rh][1], bones, ol[rh], 0, 0, 0);
    }
  }

#pragma unroll
  for (int rh = 0; rh < 2; rh++) {
    int outbase = (b * TT + qw + 16 * rh + quad * 4) * CC + h * HDD;
#pragma unroll
    for (int r = 0; r < 4; r++) {
      float l = __shfl(ol[rh][r], 0, 16);
      float inv = 1.0f / l;
      Ob[outbase + r * CC + id16]      = f2b(o[rh][0][r] * inv);
      Ob[outbase + r * CC + 16 + id16] = f2b(o[rh][1][r] * inv);
      Ob[outbase + r * CC + 32 + id16] = f2b(o[rh][2][r] * inv);
      Ob[outbase + r * CC + 48 + id16] = f2b(o[rh][3][r] * inv);
    }
  }
}

extern "C" void kernel_launch(void* const* d_in, const int* in_sizes, int n_in,
                              void* d_out, int out_size, void* d_ws, size_t ws_size,
                              hipStream_t stream) {
  const float* x     = (const float*)d_in[0];
  const float* Wqkv  = (const float*)d_in[1];
  const float* bqkv  = (const float*)d_in[2];
  const float* Wproj = (const float*)d_in[3];
  const float* bproj = (const float*)d_in[4];
  // d_in[5] = start_pos (always 0; KV-cache write+slice is identity)
  float* out = (float*)d_out;

  u16* ws = (u16*)d_ws;
  u16* xb      = ws;                              // [4096 x 768]
  u16* Wqkv_t  = xb + BB * TT * CC;               // [2304 x 768]
  u16* Wproj_t = Wqkv_t + 3 * CC * CC;            // [768 x 768]
  u16* Qb      = Wproj_t + CC * CC;               // [BH][T][64]
  u16* Kb      = Qb + BHH * TT * HDD;             // [BH][T][64]
  u16* Vt      = Kb + BHH * TT * HDD;             // [BH][64][T]
  u16* Ob      = Vt + BHH * TT * HDD;             // [4096 x 768]

  k_prep<<<3072 + 1728 + 576, 256, 0, stream>>>(x, xb, Wqkv, Wqkv_t, Wproj, Wproj_t);
  k_qkv<<<32 * 18, 256, 0, stream>>>(xb, Wqkv_t, bqkv, Qb, Kb, Vt);
  k_attn<<<16 * BHH, 128, 0, stream>>>(Qb, Kb, Vt, Ob);
  k_proj<<<32 * 6, 256, 0, stream>>>(Ob, Wproj_t, bproj, out);
}

// Round 10
// 161.908 us; speedup vs baseline: 1.0473x; 1.0002x over previous
//
#include <hip/hip_runtime.h>

// CausalSelfAttention: B=4 T=1024 C=768 NH=12 HD=64, start_pos=0.
// Round 10: k_qkv Q/K epilogue via LDS transpose -> b128 stores (was 16x b16
//   scatter/thread); XCD-aware block swizzle (m%8 = XCD) in k_qkv/k_proj so
//   each XCD's L2 holds 4 A-row-blocks + full B (~4.3 MB, ~resident).
//   k_attn/k_prep unchanged from R9 (2 waves x 32 q-rows won; R8's 384-block
//   variant regressed on grid balance).
// MFMA 16x16x32 bf16 layouts (HW-verified per guide):
//   A-op:  A[m=lane&15][k=(lane>>4)*8+j]   (8 bf16 / lane, contiguous in k)
//   B-op:  B[k=(lane>>4)*8+j][n=lane&15]   (contiguous in k)
//   C/D :  C[row=(lane>>4)*4+reg][col=lane&15]

#define BB 4
#define TT 1024
#define CC 768
#define NHH 12
#define HDD 64
#define BHH (BB*NHH)

typedef unsigned short u16;
typedef __attribute__((ext_vector_type(8))) short bf16x8;
typedef __attribute__((ext_vector_type(4))) float f32x4;

__device__ __forceinline__ u16 f2b(float f) {
  unsigned u = __float_as_uint(f);
  u += 0x7fffu + ((u >> 16) & 1u);   // RTNE
  return (u16)(u >> 16);
}
__device__ __forceinline__ u16 f2b_t(float f) {  // truncating (P values in [0,1])
  return (u16)(__float_as_uint(f) >> 16);
}

// async global->LDS, 16B per lane; LDS dest must be wave-uniform base + lane*16
__device__ __forceinline__ void gload_lds16(const u16* g, u16* l) {
  __builtin_amdgcn_global_load_lds(
      (const __attribute__((address_space(1))) unsigned int*)g,
      (__attribute__((address_space(3))) unsigned int*)l, 16, 0, 0);
}

// ---------- fused prep: x fp32->bf16 cvt  +  Wqkv / Wproj transposes ----------
__device__ __forceinline__ void tr_body(const float* __restrict__ in, u16* __restrict__ out,
                                        int R, int Cc, int bx, int by, float (*tile)[33]) {
  int c0 = bx * 32, r0 = by * 32;
  int tx = threadIdx.x & 31, ty = threadIdx.x >> 5;  // 32 x 8
#pragma unroll
  for (int i = 0; i < 32; i += 8)
    tile[ty + i][tx] = in[(r0 + ty + i) * Cc + c0 + tx];
  __syncthreads();
#pragma unroll
  for (int i = 0; i < 32; i += 8)
    out[(c0 + ty + i) * R + r0 + tx] = f2b(tile[tx][ty + i]);
}

__global__ __launch_bounds__(256) void k_prep(const float* __restrict__ x, u16* __restrict__ xb,
                                              const float* __restrict__ Wqkv, u16* __restrict__ Wqkv_t,
                                              const float* __restrict__ Wproj, u16* __restrict__ Wproj_t) {
  __shared__ float tile[32][33];
  int bid = blockIdx.x;
  if (bid < 3072) {                       // cvt: 786432 float4 groups
    int i = bid * 256 + threadIdx.x;
    float4 v = ((const float4*)x)[i];
    ushort4 o;
    o.x = f2b(v.x); o.y = f2b(v.y); o.z = f2b(v.z); o.w = f2b(v.w);
    ((ushort4*)xb)[i] = o;
  } else if (bid < 3072 + 1728) {         // Wqkv [768 x 2304] -> [2304 x 768]
    int tb = bid - 3072;
    tr_body(Wqkv, Wqkv_t, CC, 3 * CC, tb % 72, tb / 72, tile);
  } else {                                // Wproj [768 x 768] -> [768 x 768]
    int tb = bid - 4800;
    tr_body(Wproj, Wproj_t, CC, CC, tb % 24, tb / 24, tile);
  }
}

// ============ shared GEMM core: 128x128 tile, BK=32, 4 waves, 4x4 frags/wave ============
#define GEMM_CORE(A_, Bt_, m0_, n0_, SMEM)                                        \
  u16* As = (SMEM); u16* Bs = (SMEM) + 4096;                                      \
  int tid = threadIdx.x;                                                          \
  int wave = tid >> 6, lane = tid & 63, quad = lane >> 4, id16 = lane & 15;       \
  int wm = (wave & 1) * 64, wn = (wave >> 1) * 64;                                \
  const u16* ga = A_ + (m0_ + (tid >> 2)) * CC + (tid & 3) * 8;                   \
  const u16* gb = Bt_ + (n0_ + (tid >> 2)) * CC + (tid & 3) * 8;                  \
  f32x4 acc[4][4];                                                                \
  _Pragma("unroll") for (int i = 0; i < 4; i++)                                   \
      _Pragma("unroll") for (int j = 0; j < 4; j++) acc[i][j] = (f32x4){0,0,0,0}; \
  for (int k0 = 0; k0 < CC; k0 += 32) {                                           \
    gload_lds16(ga + k0, As + tid * 8);                                           \
    gload_lds16(ga + 64 * CC + k0, As + 64 * 32 + tid * 8);                       \
    gload_lds16(gb + k0, Bs + tid * 8);                                           \
    gload_lds16(gb + 64 * CC + k0, Bs + 64 * 32 + tid * 8);                       \
    __syncthreads();                                                              \
    bf16x8 af[4], bfr[4];                                                         \
    _Pragma("unroll") for (int i = 0; i < 4; i++)                                 \
        af[i] = *(const bf16x8*)(As + (wm + i * 16 + id16) * 32 + quad * 8);      \
    _Pragma("unroll") for (int j = 0; j < 4; j++)                                 \
        bfr[j] = *(const bf16x8*)(Bs + (wn + j * 16 + id16) * 32 + quad * 8);     \
    _Pragma("unroll") for (int i = 0; i < 4; i++)                                 \
        _Pragma("unroll") for (int j = 0; j < 4; j++)                             \
            acc[i][j] = __builtin_amdgcn_mfma_f32_16x16x32_bf16(af[i], bfr[j],    \
                                                                acc[i][j], 0, 0, 0); \
    __syncthreads();                                                              \
  }

// ---------- QKV GEMM: xb[4096x768] @ Wqkv_t^T + bias -> Qb/Kb (LDS transpose,
//   b128 stores) and Vt (LDS transpose to [d][t]). XCD swizzle: m%8 = XCD. ----------
__global__ __launch_bounds__(256) void k_qkv(const u16* __restrict__ A, const u16* __restrict__ Bt,
                                             const float* __restrict__ bias,
                                             u16* __restrict__ Qb, u16* __restrict__ Kb,
                                             u16* __restrict__ Vt) {
  __shared__ u16 smem[128 * 136];   // GEMM uses [0,8192); epilogues use all
  int xcd = blockIdx.x & 7, g = blockIdx.x >> 3;            // 576 blocks
  int m0 = (xcd + 8 * (g / 18)) * 128, n0 = (g % 18) * 128; // same-m0 -> same XCD
  GEMM_CORE(A, Bt, m0, n0, smem)
  float bv[4];
#pragma unroll
  for (int j = 0; j < 4; j++) bv[j] = bias[n0 + wn + j * 16 + id16];
  int bi = m0 >> 10, t0 = m0 & 1023;

  if (n0 < 2 * CC) {
    // Q or K: stage [m_local][n_local] (stride 136, 16B-aligned rows), then
    // each thread stores one 128-B contiguous [t][d] run (8 x b128).
    u16* dstb = (n0 < CC) ? Qb : Kb;
    int nrel0 = (n0 < CC) ? n0 : n0 - CC;
#pragma unroll
    for (int i = 0; i < 4; i++)
#pragma unroll
      for (int j = 0; j < 4; j++)
#pragma unroll
        for (int r = 0; r < 4; r++)
          smem[(wm + i * 16 + quad * 4 + r) * 136 + wn + j * 16 + id16] =
              f2b(acc[i][j][r] + bv[j]);
    __syncthreads();
    int m_l = tid >> 1, seg = tid & 1;
    int ng = nrel0 + seg * 64;
    u16* dst = dstb + ((bi * NHH + (ng >> 6)) * TT + t0 + m_l) * HDD;
    const u16* src = smem + m_l * 136 + seg * 64;
#pragma unroll
    for (int w2 = 0; w2 < 8; w2++)
      ((bf16x8*)dst)[w2] = ((const bf16x8*)src)[w2];
  } else {
    // V: stage transposed [n_local][m_local], then coalesced Vt[d][t] rows
#pragma unroll
    for (int i = 0; i < 4; i++)
#pragma unroll
      for (int j = 0; j < 4; j++)
#pragma unroll
        for (int r = 0; r < 4; r++)
          smem[(wn + j * 16 + id16) * 136 + wm + i * 16 + quad * 4 + r] =
              f2b(acc[i][j][r] + bv[j]);
    __syncthreads();
    int d2 = tid >> 1, seg = tid & 1;
    int h = (n0 - 2 * CC + d2) >> 6;
    int d = d2 & 63;
    u16* dst = Vt + (((bi * NHH + h) * HDD + d) * TT) + t0 + seg * 64;
    const u16* src = smem + d2 * 136 + seg * 64;
#pragma unroll
    for (int w2 = 0; w2 < 8; w2++)
      ((bf16x8*)dst)[w2] = ((const bf16x8*)src)[w2];
  }
}

// ---------- Proj GEMM: Ob[4096x768] @ Wproj_t^T + bias -> out fp32 ----------
__global__ __launch_bounds__(256) void k_proj(const u16* __restrict__ A, const u16* __restrict__ Bt,
                                              const float* __restrict__ bias, float* __restrict__ out) {
  __shared__ u16 smem[8192];
  int xcd = blockIdx.x & 7, g = blockIdx.x >> 3;           // 192 blocks
  int m0 = (xcd + 8 * (g / 6)) * 128, n0 = (g % 6) * 128;  // same-m0 -> same XCD
  GEMM_CORE(A, Bt, m0, n0, smem)
  float bv[4];
#pragma unroll
  for (int j = 0; j < 4; j++) bv[j] = bias[n0 + wn + j * 16 + id16];
#pragma unroll
  for (int i = 0; i < 4; i++) {
#pragma unroll
    for (int j = 0; j < 4; j++) {
#pragma unroll
      for (int r = 0; r < 4; r++) {
        int m = m0 + wm + i * 16 + quad * 4 + r;
        int n = n0 + wn + j * 16 + id16;
        out[m * CC + n] = acc[i][j][r] + bv[j];
      }
    }
  }
}

// ---------- Flash attention: 64 q-rows/block, 2 waves x 32 rows (R9, unchanged) ----------
#define PSTR 72
__global__ __launch_bounds__(128) void k_attn(const u16* __restrict__ Qb, const u16* __restrict__ Kb,
                                              const u16* __restrict__ Vt, u16* __restrict__ Ob) {
  __shared__ __align__(16) u16 Ks[2][64 * 64];    // [buf][key][d]
  __shared__ __align__(16) u16 Vs[2][64 * 64];    // [buf][d][key]
  __shared__ __align__(16) u16 Pl[2][32 * PSTR];  // per-wave P (32 x 64, stride 72)
  int tid = threadIdx.x;
  int wave = tid >> 6, lane = tid & 63, quad = lane >> 4, id16 = lane & 15;
  int bh = blockIdx.x % BHH, t = 15 - (blockIdx.x / BHH);
  int b = bh / NHH, h = bh % NHH;
  int qw = t * 64 + wave * 32;      // this wave's first q row
  int nch = t + 1;                  // 64-key chunks this block runs
  const float cexp = 0.125f * 1.44269504088896f;  // scale * log2(e)
  short onev = (id16 == 0) ? (short)0x3F80 : (short)0;  // bf16 1.0 on col 0
  bf16x8 bones = {onev, onev, onev, onev, onev, onev, onev, onev};

  const u16* Kg = Kb + (bh * TT) * HDD;        // [T][64]
  const u16* Vg = Vt + (bh * HDD) * TT;        // [64][T]
  int srow = tid >> 3, spart = tid & 7;        // staging coords (16 rows/gload)

  bf16x8 aq[2][2];
#pragma unroll
  for (int rh = 0; rh < 2; rh++) {
    const u16* Qrow = Qb + (bh * TT + qw + 16 * rh + id16) * HDD;
    aq[rh][0] = *(const bf16x8*)(Qrow + quad * 8);
    aq[rh][1] = *(const bf16x8*)(Qrow + 32 + quad * 8);
  }
  f32x4 o[2][4], ol[2];
#pragma unroll
  for (int rh = 0; rh < 2; rh++) {
    ol[rh] = (f32x4){0,0,0,0};
#pragma unroll
    for (int dt = 0; dt < 4; dt++) o[rh][dt] = (f32x4){0,0,0,0};
  }

  // stage chunk 0 into buf 0: K 4 gloads (16 key-rows each), V 4 gloads (16 d-rows each)
#pragma unroll
  for (int i = 0; i < 4; i++) {
    gload_lds16(Kg + (16 * i + srow) * HDD + spart * 8, Ks[0] + i * 1024 + tid * 8);
    gload_lds16(Vg + (16 * i + srow) * TT + spart * 8, Vs[0] + i * 1024 + tid * 8);
  }

  for (int c = 0; c < nch; c++) {
    __syncthreads();
    if (c + 1 < nch) {
      int kb = (c + 1) * 64;
      u16* kd = Ks[(c + 1) & 1];
      u16* vd = Vs[(c + 1) & 1];
#pragma unroll
      for (int i = 0; i < 4; i++) {
        gload_lds16(Kg + (kb + 16 * i + srow) * HDD + spart * 8, kd + i * 1024 + tid * 8);
        gload_lds16(Vg + (16 * i + srow) * TT + kb + spart * 8, vd + i * 1024 + tid * 8);
      }
    }
    const u16* kbuf = Ks[c & 1];
    const u16* vbuf = Vs[c & 1];

    // K frags: read once, reused for both row-halves
    bf16x8 kf0[4], kf1[4];
#pragma unroll
    for (int kt = 0; kt < 4; kt++) {
      kf0[kt] = *(const bf16x8*)(kbuf + (kt * 16 + id16) * 64 + quad * 8);
      kf1[kt] = *(const bf16x8*)(kbuf + (kt * 16 + id16) * 64 + 32 + quad * 8);
    }

    u16* Pb = Pl[wave];
    bool diag = (c == nch - 1);
#pragma unroll
    for (int rh = 0; rh < 2; rh++) {
      f32x4 s[4];
#pragma unroll
      for (int kt = 0; kt < 4; kt++) {
        f32x4 z = {0,0,0,0};
        z = __builtin_amdgcn_mfma_f32_16x16x32_bf16(aq[rh][0], kf0[kt], z, 0, 0, 0);
        s[kt] = __builtin_amdgcn_mfma_f32_16x16x32_bf16(aq[rh][1], kf1[kt], z, 0, 0, 0);
      }
      if (!diag) {
#pragma unroll
        for (int kt = 0; kt < 4; kt++)
#pragma unroll
          for (int r = 0; r < 4; r++)
            Pb[(16 * rh + quad * 4 + r) * PSTR + kt * 16 + id16] =
                f2b_t(__builtin_amdgcn_exp2f(s[kt][r] * cexp));
      } else {
        int kb = c * 64;
#pragma unroll
        for (int kt = 0; kt < 4; kt++) {
          int col = kb + kt * 16 + id16;
#pragma unroll
          for (int r = 0; r < 4; r++) {
            float p = __builtin_amdgcn_exp2f(s[kt][r] * cexp);
            p = (col <= qw + 16 * rh + quad * 4 + r) ? p : 0.f;
            Pb[(16 * rh + quad * 4 + r) * PSTR + kt * 16 + id16] = f2b_t(p);
          }
        }
      }
    }
    asm volatile("s_waitcnt lgkmcnt(0)" ::: "memory");

    bf16x8 pf[2][2];
#pragma unroll
    for (int rh = 0; rh < 2; rh++) {
      pf[rh][0] = *(const bf16x8*)(Pb + (16 * rh + id16) * PSTR + quad * 8);
      pf[rh][1] = *(const bf16x8*)(Pb + (16 * rh + id16) * PSTR + 32 + quad * 8);
    }
    // O += P @ V: V frags read once, reused for both row-halves; l via ones
#pragma unroll
    for (int dt = 0; dt < 4; dt++) {
      bf16x8 vf0 = *(const bf16x8*)(vbuf + (dt * 16 + id16) * 64 + quad * 8);
      bf16x8 vf1 = *(const bf16x8*)(vbuf + (dt * 16 + id16) * 64 + 32 + quad * 8);
#pragma unroll
      for (int rh = 0; rh < 2; rh++) {
        o[rh][dt] = __builtin_amdgcn_mfma_f32_16x16x32_bf16(pf[rh][0], vf0, o[rh][dt], 0, 0, 0);
        o[rh][dt] = __builtin_amdgcn_mfma_f32_16x16x32_bf16(pf[rh][1], vf1, o[rh][dt], 0, 0, 0);
      }
    }
#pragma unroll
    for (int rh = 0; rh < 2; rh++) {
      ol[rh] = __builtin_amdgcn_mfma_f32_16x16x32_bf16(pf[rh][0], bones, ol[rh], 0, 0, 0);
      ol[rh] = __builtin_amdgcn_mfma_f32_16x16x32_bf16(pf[rh][1], bones, ol[rh], 0, 0, 0);
    }
  }

#pragma unroll
  for (int rh = 0; rh < 2; rh++) {
    int outbase = (b * TT + qw + 16 * rh + quad * 4) * CC + h * HDD;
#pragma unroll
    for (int r = 0; r < 4; r++) {
      float l = __shfl(ol[rh][r], 0, 16);
      float inv = 1.0f / l;
      Ob[outbase + r * CC + id16]      = f2b(o[rh][0][r] * inv);
      Ob[outbase + r * CC + 16 + id16] = f2b(o[rh][1][r] * inv);
      Ob[outbase + r * CC + 32 + id16] = f2b(o[rh][2][r] * inv);
      Ob[outbase + r * CC + 48 + id16] = f2b(o[rh][3][r] * inv);
    }
  }
}

extern "C" void kernel_launch(void* const* d_in, const int* in_sizes, int n_in,
                              void* d_out, int out_size, void* d_ws, size_t ws_size,
                              hipStream_t stream) {
  const float* x     = (const float*)d_in[0];
  const float* Wqkv  = (const float*)d_in[1];
  const float* bqkv  = (const float*)d_in[2];
  const float* Wproj = (const float*)d_in[3];
  const float* bproj = (const float*)d_in[4];
  // d_in[5] = start_pos (always 0; KV-cache write+slice is identity)
  float* out = (float*)d_out;

  u16* ws = (u16*)d_ws;
  u16* xb      = ws;                              // [4096 x 768]
  u16* Wqkv_t  = xb + BB * TT * CC;               // [2304 x 768]
  u16* Wproj_t = Wqkv_t + 3 * CC * CC;            // [768 x 768]
  u16* Qb      = Wproj_t + CC * CC;               // [BH][T][64]
  u16* Kb      = Qb + BHH * TT * HDD;             // [BH][T][64]
  u16* Vt      = Kb + BHH * TT * HDD;             // [BH][64][T]
  u16* Ob      = Vt + BHH * TT * HDD;             // [4096 x 768]

  k_prep<<<3072 + 1728 + 576, 256, 0, stream>>>(x, xb, Wqkv, Wqkv_t, Wproj, Wproj_t);
  k_qkv<<<32 * 18, 256, 0, stream>>>(xb, Wqkv_t, bqkv, Qb, Kb, Vt);
  k_attn<<<16 * BHH, 128, 0, stream>>>(Qb, Kb, Vt, Ob);
  k_proj<<<32 * 6, 256, 0, stream>>>(Ob, Wproj_t, bproj, out);
}